// Round 3
// baseline (165.197 us; speedup 1.0000x reference)
//
#include <hip/hip_runtime.h>
#include <hip/hip_bf16.h>

#define N_CHR 23
#define N_EMB 512   // K (codebook)
#define E_DIM 128   // E
#define B_SZ  4
#define L_SEQ 2048

typedef __attribute__((ext_vector_type(8))) short short8;
typedef __attribute__((ext_vector_type(4))) float floatx4;

__device__ __forceinline__ float bf2f(unsigned short u) {
    return __uint_as_float(((unsigned)u) << 16);
}
__device__ __forceinline__ unsigned short f2bf(float f) {
    unsigned u = __float_as_uint(f);
    unsigned r = u + 0x7FFFu + ((u >> 16) & 1u);
    return (unsigned short)(r >> 16);
}

// One block: 4 waves, tile = 64 rows (L) x 128 cols (E), K-loop over 512 in
// chunks of 32. Fused: p = exp(exp(-(pos-ctr)^2/(2*var))) built in-register in
// MFMA A-operand layout (softmax over rbf in [0,1] needs no max-subtraction);
// emb chunk (fp32 storage, bf16-rounded values) packed to bf16 and staged to
// LDS in fragment-linear order; softmax denominator carried in fp32 (from the
// bf16-rounded p, so numerator/denominator are consistent).
// Inputs fp32 storage; OUTPUT fp32 storage (round-2 lesson: d_out is float*).
__global__ __launch_bounds__(256, 4) void rbf_emb_kernel(
    const float* __restrict__ pos,   // [B, C, L]  f32
    const float* __restrict__ emb,   // [C, K, E]  f32
    const float* __restrict__ ctr,   // [C, K]     f32
    const float* __restrict__ lvar,  // [C, K]     f32
    float* __restrict__ out)         // [B, C*L, E] f32
{
    __shared__ float centers_s[N_EMB];
    __shared__ float scale_s[N_EMB];          // -1/(2*var)
    __shared__ uint4 Bs[2][512];              // 2 x (32x128 bf16) frag-linear, 8KB each
    __shared__ float inv_s[64];

    const int tid  = threadIdx.x;
    const int lane = tid & 63;
    const int wave = tid >> 6;
    const int quad = lane >> 4;
    const int m    = lane & 15;

    const int bc   = blockIdx.x >> 5;   // 0..91  (b*23 + c)
    const int mt   = blockIdx.x & 31;   // 0..31
    const int c    = bc % N_CHR;
    const int row0 = mt * 64;

    // prologue: stage per-chromosome centers and -1/(2*sigma^2)
    for (int k = tid; k < N_EMB; k += 256) {
        centers_s[k] = ctr[c * N_EMB + k];
        scale_s[k]   = -0.5f * __expf(-lvar[c * N_EMB + k]);
    }

    const int   myrow = row0 + wave * 16 + m;                 // row in [0,2048)
    const float posf  = pos[bc * L_SEQ + myrow];

    floatx4 acc[8];
#pragma unroll
    for (int i = 0; i < 8; ++i) acc[i] = (floatx4){0.f, 0.f, 0.f, 0.f};
    float denom = 0.f;

    __syncthreads();

    const int n_st = tid & 127;     // staging column (E)
    const int qd0  = tid >> 7;      // 0/1 -> handles quads {qd0, qd0+2}
    const float* embc = emb + (size_t)c * (N_EMB * E_DIM);

    for (int ch = 0; ch < 16; ++ch) {
        const int kc = ch * 32;
        uint4* bw = Bs[ch & 1];

        // --- stage B chunk [32 x 128] f32 -> bf16 -> LDS (fragment-linear) ---
        // frag-linear: offset16B = ntile*64 + quad*16 + (n&15); read is lane-linear.
#pragma unroll
        for (int qq = 0; qq < 2; ++qq) {
            const int qd = qd0 + qq * 2;
            const float* src = embc + (kc + qd * 8) * E_DIM + n_st;
            unsigned v[8];
#pragma unroll
            for (int j = 0; j < 8; ++j) v[j] = (unsigned)f2bf(src[j * E_DIM]); // coalesced per j
            uint4 w;
            w.x = v[0] | (v[1] << 16);
            w.y = v[2] | (v[3] << 16);
            w.z = v[4] | (v[5] << 16);
            w.w = v[6] | (v[7] << 16);
            bw[((n_st >> 4) << 6) + (qd << 4) + (n_st & 15)] = w;
        }

        // --- compute A fragment in-register: A[m=lane&15][k=quad*8+j] ---
        short8 afrag;
#pragma unroll
        for (int j = 0; j < 8; ++j) {
            const int   k   = kc + quad * 8 + j;
            const float d   = posf - centers_s[k];
            const float rbf = __expf(d * d * scale_s[k]);   // in (0,1]
            const float p   = __expf(rbf);                  // in [1,e] -> no max needed
            const unsigned short pb = f2bf(p);
            afrag[j] = (short)pb;
            denom += bf2f(pb);       // denom consistent with bf16 numerator
        }

        __syncthreads();   // Bs[ch&1] ready; prev buffer's reads drained

        const uint4* br = bw;
#pragma unroll
        for (int nt = 0; nt < 8; ++nt) {
            short8 bfrag = *(const short8*)&br[(nt << 6) + lane];  // ds_read_b128
            acc[nt] = __builtin_amdgcn_mfma_f32_16x16x32_bf16(afrag, bfrag, acc[nt], 0, 0, 0);
        }
    }

    // --- softmax denominator: lanes sharing m (quads 0..3) hold partials ---
    denom += __shfl_xor(denom, 16);
    denom += __shfl_xor(denom, 32);
    if (lane < 16) inv_s[wave * 16 + m] = 1.0f / denom;
    __syncthreads();

    // --- epilogue: C/D layout col = lane&15, row = quad*4 + reg; fp32 stores ---
    float* outp = out + (size_t)(bc * L_SEQ + row0 + wave * 16) * E_DIM;
#pragma unroll
    for (int reg = 0; reg < 4; ++reg) {
        const int   r   = quad * 4 + reg;
        const float inv = inv_s[wave * 16 + r];
        float* o = outp + r * E_DIM + m;
#pragma unroll
        for (int nt = 0; nt < 8; ++nt) {
            o[nt * 16] = acc[nt][reg] * inv;
        }
    }
}

extern "C" void kernel_launch(void* const* d_in, const int* in_sizes, int n_in,
                              void* d_out, int out_size, void* d_ws, size_t ws_size,
                              hipStream_t stream) {
    // d_in: [0]=chromosome(int32, unused), [1]=position(f32), [2]=embeddings(f32),
    //       [3]=centers(f32), [4]=log_variances(f32)
    const float* pos  = (const float*)d_in[1];
    const float* emb  = (const float*)d_in[2];
    const float* ctr  = (const float*)d_in[3];
    const float* lvar = (const float*)d_in[4];
    float* out = (float*)d_out;

    const int blocks = (B_SZ * N_CHR) * (L_SEQ / 64);   // 92 * 32 = 2944
    rbf_emb_kernel<<<blocks, 256, 0, stream>>>(pos, emb, ctr, lvar, out);
}

// Round 4
// 145.881 us; speedup vs baseline: 1.1324x; 1.1324x over previous
//
#include <hip/hip_runtime.h>
#include <hip/hip_bf16.h>

#define N_CHR 23
#define N_EMB 512   // K (codebook)
#define E_DIM 128   // E
#define B_SZ  4
#define L_SEQ 2048
#define LOG2E 1.4426950408889634f

typedef __attribute__((ext_vector_type(8))) short short8;
typedef __attribute__((ext_vector_type(4))) float floatx4;

#if __has_builtin(__builtin_amdgcn_exp2f)
#define EXP2(x) __builtin_amdgcn_exp2f(x)
#else
#define EXP2(x) __expf((x) * 0.6931471805599453f)
#endif

__device__ __forceinline__ float bf2f(unsigned short u) {
    return __uint_as_float(((unsigned)u) << 16);
}
__device__ __forceinline__ unsigned short f2bf(float f) {
    unsigned u = __float_as_uint(f);
    unsigned r = u + 0x7FFFu + ((u >> 16) & 1u);
    return (unsigned short)(r >> 16);
}

// ---------------- Pre-pass: emb fp32 -> bf16, MFMA-B-fragment-linear ----------
// embw[((c*16 + ch)*8 + nt)*64 + lane] (uint4) holds B[k=ch*32+quad*8+j][n=nt*16+(lane&15)]
// for j=0..7 packed as 8 bf16 (j ascending, low half first) — exactly the uint4 the
// main kernel's lane reads as its B fragment. 23*16*8*64 = 188416 uint4 = 2.9 MB.
__global__ __launch_bounds__(256) void emb_pack_kernel(
    const float* __restrict__ emb, uint4* __restrict__ embw)
{
    const int idx  = blockIdx.x * 256 + threadIdx.x;
    const int lane = idx & 63;
    const int nt   = (idx >> 6) & 7;
    const int ch   = (idx >> 9) & 15;
    const int c    = idx >> 13;
    if (c >= N_CHR) return;
    const int quad = lane >> 4;
    const int n    = nt * 16 + (lane & 15);
    const float* src = emb + (size_t)(c * N_EMB + ch * 32 + quad * 8) * E_DIM + n;
    unsigned v[8];
#pragma unroll
    for (int j = 0; j < 8; ++j) v[j] = (unsigned)f2bf(src[j * E_DIM]);
    uint4 w;
    w.x = v[0] | (v[1] << 16);
    w.y = v[2] | (v[3] << 16);
    w.z = v[4] | (v[5] << 16);
    w.w = v[6] | (v[7] << 16);
    embw[idx] = w;
}

// ---------------- Main kernel: async B staging, in-register A (exp chain) -----
__global__ __launch_bounds__(256, 4) void rbf_emb_kernel(
    const float* __restrict__ pos,   // [B, C, L]  f32
    const uint4* __restrict__ embw,  // pre-packed bf16 frag-linear
    const float* __restrict__ ctr,   // [C, K]     f32
    const float* __restrict__ lvar,  // [C, K]     f32
    float* __restrict__ out)         // [B, C*L, E] f32
{
    __shared__ float2 cs_s[N_EMB];   // {center, -log2e/(2*var)}  4KB
    __shared__ uint4 Bs[2][512];     // double-buffered 32x128 bf16 chunk, 16KB
    __shared__ float inv_s[64];

    const int tid  = threadIdx.x;
    const int lane = tid & 63;
    const int wave = tid >> 6;
    const int quad = lane >> 4;
    const int m    = lane & 15;

    const int bc   = blockIdx.x >> 5;   // 0..91  (b*23 + c)
    const int mt   = blockIdx.x & 31;   // 0..31
    const int c    = bc % N_CHR;
    const int row0 = mt * 64;

    for (int k = tid; k < N_EMB; k += 256) {
        cs_s[k] = make_float2(ctr[c * N_EMB + k],
                              -0.5f * LOG2E * __expf(-lvar[c * N_EMB + k]));
    }

    const int   myrow = row0 + wave * 16 + m;
    const float posf  = pos[bc * L_SEQ + myrow];

    floatx4 acc[8];
#pragma unroll
    for (int i = 0; i < 8; ++i) acc[i] = (floatx4){0.f, 0.f, 0.f, 0.f};
    float denom = 0.f;

    __syncthreads();

    const uint4*  gbase = embw + (size_t)c * (16 * 8 * 64);
    const float2* csq   = cs_s + quad * 8;

    for (int ch = 0; ch < 16; ++ch) {
        const int kc = ch * 32;
        uint4* bw = Bs[ch & 1];

        // --- async stage B chunk: 8 segs of 64 lanes x 16B; wave w does segs 2w,2w+1 ---
        {
            const uint4* g = gbase + ch * 512 + wave * 128 + lane;
            __builtin_amdgcn_global_load_lds(
                (const __attribute__((address_space(1))) void*)(g),
                (__attribute__((address_space(3))) void*)(bw + wave * 128), 16, 0, 0);
            __builtin_amdgcn_global_load_lds(
                (const __attribute__((address_space(1))) void*)(g + 64),
                (__attribute__((address_space(3))) void*)(bw + wave * 128 + 64), 16, 0, 0);
        }

        // --- A fragment in-register: A[m=lane&15][k=quad*8+j] (overlaps the async loads) ---
        unsigned pk[4];
#pragma unroll
        for (int jj = 0; jj < 4; ++jj) {
            const float2 cs0 = csq[kc + 2 * jj];
            const float2 cs1 = csq[kc + 2 * jj + 1];
            const float d0 = posf - cs0.x;
            const float d1 = posf - cs1.x;
            const float p0 = EXP2(EXP2(d0 * d0 * cs0.y) * LOG2E);  // exp(rbf), rbf=exp(-d^2/2v)
            const float p1 = EXP2(EXP2(d1 * d1 * cs1.y) * LOG2E);
            const unsigned u0 = __float_as_uint(p0);
            const unsigned u1 = __float_as_uint(p1);
            const unsigned r0 = (u0 + 0x7FFFu + ((u0 >> 16) & 1u)) >> 16;          // bf16 RNE
            const unsigned r1 = (u1 + 0x7FFFu + ((u1 >> 16) & 1u)) & 0xFFFF0000u;  // bf16 RNE, high
            pk[jj] = r0 | r1;
            denom += __uint_as_float(r0 << 16) + __uint_as_float(r1);  // consistent w/ numerator
        }
        const int4 pkv = make_int4((int)pk[0], (int)pk[1], (int)pk[2], (int)pk[3]);
        const short8 afrag = __builtin_bit_cast(short8, pkv);

        __syncthreads();   // drains vmcnt (async LDS writes) + prior buffer reads

        const uint4* br = bw;
#pragma unroll
        for (int nt = 0; nt < 8; ++nt) {
            short8 bfrag = *(const short8*)&br[(nt << 6) + lane];  // ds_read_b128
            acc[nt] = __builtin_amdgcn_mfma_f32_16x16x32_bf16(afrag, bfrag, acc[nt], 0, 0, 0);
        }
    }

    // --- softmax denominator: quads hold partials of the same 16 rows ---
    denom += __shfl_xor(denom, 16);
    denom += __shfl_xor(denom, 32);
    if (lane < 16) inv_s[wave * 16 + m] = 1.0f / denom;
    __syncthreads();

    // --- epilogue: C/D layout col = lane&15, row = quad*4 + reg ---
    float* outp = out + (size_t)(bc * L_SEQ + row0 + wave * 16) * E_DIM;
#pragma unroll
    for (int reg = 0; reg < 4; ++reg) {
        const int   r   = quad * 4 + reg;
        const float inv = inv_s[wave * 16 + r];
        float* o = outp + r * E_DIM + m;
#pragma unroll
        for (int nt = 0; nt < 8; ++nt) {
            o[nt * 16] = acc[nt][reg] * inv;
        }
    }
}

// ---------------- Fallback (round-3 kernel, used if ws too small) -------------
__global__ __launch_bounds__(256, 4) void rbf_emb_kernel_slow(
    const float* __restrict__ pos, const float* __restrict__ emb,
    const float* __restrict__ ctr, const float* __restrict__ lvar,
    float* __restrict__ out)
{
    __shared__ float centers_s[N_EMB];
    __shared__ float scale_s[N_EMB];
    __shared__ uint4 Bs[2][512];
    __shared__ float inv_s[64];

    const int tid  = threadIdx.x;
    const int lane = tid & 63;
    const int wave = tid >> 6;
    const int quad = lane >> 4;
    const int m    = lane & 15;
    const int bc   = blockIdx.x >> 5;
    const int mt   = blockIdx.x & 31;
    const int c    = bc % N_CHR;
    const int row0 = mt * 64;

    for (int k = tid; k < N_EMB; k += 256) {
        centers_s[k] = ctr[c * N_EMB + k];
        scale_s[k]   = -0.5f * __expf(-lvar[c * N_EMB + k]);
    }
    const float posf = pos[bc * L_SEQ + row0 + wave * 16 + m];
    floatx4 acc[8];
#pragma unroll
    for (int i = 0; i < 8; ++i) acc[i] = (floatx4){0.f, 0.f, 0.f, 0.f};
    float denom = 0.f;
    __syncthreads();

    const int n_st = tid & 127;
    const int qd0  = tid >> 7;
    const float* embc = emb + (size_t)c * (N_EMB * E_DIM);

    for (int ch = 0; ch < 16; ++ch) {
        const int kc = ch * 32;
        uint4* bw = Bs[ch & 1];
#pragma unroll
        for (int qq = 0; qq < 2; ++qq) {
            const int qd = qd0 + qq * 2;
            const float* src = embc + (kc + qd * 8) * E_DIM + n_st;
            unsigned v[8];
#pragma unroll
            for (int j = 0; j < 8; ++j) v[j] = (unsigned)f2bf(src[j * E_DIM]);
            uint4 w;
            w.x = v[0] | (v[1] << 16);
            w.y = v[2] | (v[3] << 16);
            w.z = v[4] | (v[5] << 16);
            w.w = v[6] | (v[7] << 16);
            bw[((n_st >> 4) << 6) + (qd << 4) + (n_st & 15)] = w;
        }
        short8 afrag;
#pragma unroll
        for (int j = 0; j < 8; ++j) {
            const int   k   = kc + quad * 8 + j;
            const float d   = posf - centers_s[k];
            const float rbf = __expf(d * d * scale_s[k]);
            const float p   = __expf(rbf);
            const unsigned short pb = f2bf(p);
            afrag[j] = (short)pb;
            denom += bf2f(pb);
        }
        __syncthreads();
        const uint4* br = bw;
#pragma unroll
        for (int nt = 0; nt < 8; ++nt) {
            short8 bfrag = *(const short8*)&br[(nt << 6) + lane];
            acc[nt] = __builtin_amdgcn_mfma_f32_16x16x32_bf16(afrag, bfrag, acc[nt], 0, 0, 0);
        }
    }
    denom += __shfl_xor(denom, 16);
    denom += __shfl_xor(denom, 32);
    if (lane < 16) inv_s[wave * 16 + m] = 1.0f / denom;
    __syncthreads();
    float* outp = out + (size_t)(bc * L_SEQ + row0 + wave * 16) * E_DIM;
#pragma unroll
    for (int reg = 0; reg < 4; ++reg) {
        const int   r   = quad * 4 + reg;
        const float inv = inv_s[wave * 16 + r];
        float* o = outp + r * E_DIM + m;
#pragma unroll
        for (int nt = 0; nt < 8; ++nt) o[nt * 16] = acc[nt][reg] * inv;
    }
}

extern "C" void kernel_launch(void* const* d_in, const int* in_sizes, int n_in,
                              void* d_out, int out_size, void* d_ws, size_t ws_size,
                              hipStream_t stream) {
    // d_in: [0]=chromosome(int32, unused), [1]=position(f32), [2]=embeddings(f32),
    //       [3]=centers(f32), [4]=log_variances(f32)
    const float* pos  = (const float*)d_in[1];
    const float* emb  = (const float*)d_in[2];
    const float* ctr  = (const float*)d_in[3];
    const float* lvar = (const float*)d_in[4];
    float* out = (float*)d_out;

    const int    blocks   = (B_SZ * N_CHR) * (L_SEQ / 64);        // 2944
    const size_t ws_needed = (size_t)N_CHR * 16 * 8 * 64 * 16;    // 2.9 MB

    if (ws_size >= ws_needed) {
        uint4* embw = (uint4*)d_ws;
        emb_pack_kernel<<<(N_CHR * 16 * 8 * 64) / 256, 256, 0, stream>>>(emb, embw);
        rbf_emb_kernel<<<blocks, 256, 0, stream>>>(pos, embw, ctr, lvar, out);
    } else {
        rbf_emb_kernel_slow<<<blocks, 256, 0, stream>>>(pos, emb, ctr, lvar, out);
    }
}